// Round 16
// baseline (136.609 us; speedup 1.0000x reference)
//
#include <hip/hip_runtime.h>
#include <math.h>

#define HH 24
#define LLEN 2048
#define DD 128
#define BLK 64
#define NBLK 32
#define TOPK 16
#define NCHUNK 16

typedef __attribute__((ext_vector_type(8))) short bf16x8;
typedef __attribute__((ext_vector_type(4))) float f32x4;

typedef unsigned int u32_g __attribute__((address_space(1)));
typedef unsigned int u32_l __attribute__((address_space(3)));

__device__ __forceinline__ unsigned short f2bf(float f) {
    unsigned u = __builtin_bit_cast(unsigned, f);
    unsigned r = (u + 0x7FFFu + ((u >> 16) & 1u)) >> 16;
    return (unsigned short)r;
}
__device__ __forceinline__ float bf2f(unsigned short b) {
    unsigned u = ((unsigned)b) << 16;
    return __builtin_bit_cast(float, u);
}
// async 16B/lane global->LDS: lds base is WAVE-UNIFORM (lane0); HW adds lane*16.
__device__ __forceinline__ void gload16(unsigned short* lds, const unsigned short* g) {
    __builtin_amdgcn_global_load_lds((const u32_g*)g, (u32_l*)lds, 16, 0, 0);
}

// ---------------- 1: convert K/V to bf16 (pre-swizzled) + block pooling (r11) ----------------
// kb16[h][l][chunk^(l&7)] row-major bf16; vt16[h][ktile][d][keychunk^(d&7)] transposed bf16.
__global__ __launch_bounds__(256) void convert_pool(
    const float* __restrict__ q, const float* __restrict__ k, const float* __restrict__ v,
    unsigned short* __restrict__ kb16, unsigned short* __restrict__ vt16,
    float* __restrict__ qb, float* __restrict__ kb)
{
    const int nb = blockIdx.x, h = blockIdx.y;
    const int l0 = nb * BLK;
    const int tid = threadIdx.x;
    __shared__ unsigned short vt_s[DD * BLK];  // 16 KB

    // ---- K convert: swizzled row writes ----
    {
        const int r = tid >> 2, c0 = (tid & 3) * 4;
        const float* kp = k + ((size_t)(l0 + r) * HH + h) * DD + c0 * 8;
        unsigned short* krow = kb16 + ((size_t)h * LLEN + l0 + r) * DD;
        #pragma unroll
        for (int j = 0; j < 4; ++j) {
            float4 a = *(const float4*)(kp + j * 8);
            float4 c = *(const float4*)(kp + j * 8 + 4);
            unsigned short tmp[8] = {f2bf(a.x), f2bf(a.y), f2bf(a.z), f2bf(a.w),
                                     f2bf(c.x), f2bf(c.y), f2bf(c.z), f2bf(c.w)};
            const int chunk = (c0 + j) ^ (r & 7);
            *(bf16x8*)&krow[chunk * 8] = *(bf16x8*)tmp;
        }
    }
    // ---- V transpose via LDS bounce (packed key-pair u32 writes, swizzled) ----
    {
        const int kp2 = tid >> 3, dgb = tid & 7;
        const float* v0p = v + ((size_t)(l0 + kp2 * 2) * HH + h) * DD;
        const float* v1p = v0p + (size_t)HH * DD;
        #pragma unroll
        for (int j2 = 0; j2 < 4; ++j2) {
            const int d0 = dgb * 4 + j2 * 32;
            float4 a = *(const float4*)(v0p + d0);
            float4 c = *(const float4*)(v1p + d0);
            float a4[4] = {a.x, a.y, a.z, a.w}, c4[4] = {c.x, c.y, c.z, c.w};
            #pragma unroll
            for (int i = 0; i < 4; ++i) {
                unsigned pak = (unsigned)f2bf(a4[i]) | ((unsigned)f2bf(c4[i]) << 16);
                const int d = d0 + i;
                const int chunk = (kp2 >> 2) ^ (d & 7);
                *(unsigned*)&vt_s[d * BLK + chunk * 8 + (kp2 & 3) * 2] = pak;
            }
        }
    }
    __syncthreads();
    // copy-out keeps the swizzle: LDS stage in sla_attn is a linear copy (rule #21)
    {
        bf16x8* dstv = (bf16x8*)(vt16 + (size_t)(h * NBLK + nb) * DD * BLK);
        const bf16x8* srcv = (const bf16x8*)vt_s;
        #pragma unroll
        for (int j = 0; j < 4; ++j) dstv[tid * 4 + j] = srcv[tid * 4 + j];
    }
    __syncthreads();
    // ---- block-sum pooling (L1-hot re-read) ----
    {
        float* ps = (float*)vt_s;
        const int d = tid & 127, half = tid >> 7;
        const size_t rs = (size_t)HH * DD;
        const float* qp = q + ((size_t)(l0 + half * 32) * HH + h) * DD + d;
        const float* kp = k + ((size_t)(l0 + half * 32) * HH + h) * DD + d;
        float sq = 0.f, sk = 0.f;
        #pragma unroll 8
        for (int i = 0; i < 32; ++i) { sq += qp[i * rs]; sk += kp[i * rs]; }
        ps[half * 128 + d] = sq;
        ps[256 + half * 128 + d] = sk;
        __syncthreads();
        if (half == 0) {
            qb[((size_t)h * NBLK + nb) * DD + d] = ps[d] + ps[128 + d];
            kb[((size_t)h * NBLK + nb) * DD + d] = ps[256 + d] + ps[384 + d];
        }
    }
}

// ---------------- 1b: block scores + top-16 LUT ----------------
__global__ __launch_bounds__(256) void topk_kernel(
    const float* __restrict__ qb, const float* __restrict__ kb, int* __restrict__ lut)
{
    const int h = blockIdx.x;
    __shared__ float kb_s[NBLK][DD];
    __shared__ float sc[NBLK][NBLK];
    const int tid = threadIdx.x;
    for (int f = tid; f < NBLK * DD / 4; f += 256)
        ((float4*)kb_s)[f] = ((const float4*)(kb + (size_t)h * NBLK * DD))[f];
    __syncthreads();
    for (int p = tid; p < NBLK * NBLK; p += 256) {
        const int iq = p >> 5, ik = p & 31;
        const float4* qr4 = (const float4*)(qb + ((size_t)h * NBLK + iq) * DD);
        const float4* kr4 = (const float4*)&kb_s[ik][0];
        float s = 0.f;
        for (int dq = 0; dq < DD / 4; ++dq) {
            float4 a = qr4[dq], b = kr4[dq];
            s += a.x * b.x + a.y * b.y + a.z * b.z + a.w * b.w;
        }
        sc[iq][ik] = s;
    }
    __syncthreads();
    if (tid < NBLK) {
        const int iq = tid;
        for (int t = 0; t < TOPK; ++t) {
            float bv = -1e30f; int bi = 0;
            for (int j = 0; j < NBLK; ++j) {
                float s = sc[iq][j];
                if (s > bv) { bv = s; bi = j; }
            }
            lut[((size_t)h * NBLK + iq) * TOPK + t] = bi;
            sc[iq][bi] = -1e30f;
        }
    }
}

// ---------------- 2: kvsum partials via MFMA (K from L2-warm kb16; bf16 partials) ----------------
__global__ __launch_bounds__(256, 2) void kv_mfma(
    const unsigned short* __restrict__ kb16, const unsigned short* __restrict__ vt16,
    unsigned short* __restrict__ kvp, float* __restrict__ ksp)
{
    const int h = blockIdx.x, c = blockIdx.y;
    __shared__ unsigned short klT[DD * DD];  // [d][l] swizzled, 32 KB
    const int tid = threadIdx.x;
    const int quad = tid >> 3, dpart = tid & 7;
    const int d0 = dpart * 16;
    const int wid = tid >> 6, lane = tid & 63;
    const int l15 = lane & 15, g = lane >> 4;

    f32x4 acc[2][8];
    #pragma unroll
    for (int mi = 0; mi < 2; ++mi)
        #pragma unroll
        for (int nt = 0; nt < 8; ++nt) acc[mi][nt] = (f32x4){0.f, 0.f, 0.f, 0.f};
    float ksa[16];
    #pragma unroll
    for (int j = 0; j < 16; ++j) ksa[j] = 0.f;

    const int l0 = c * DD;
    {
        const int lr = quad * 4;
        float rows[4][16];
        // read K from kb16 (swizzled row chunks: pos = chunk ^ (l&7)); l&7 == (lr+i)&7
        #pragma unroll
        for (int i = 0; i < 4; ++i) {
            const unsigned short* krow = kb16 + ((size_t)h * LLEN + l0 + lr + i) * DD;
            const int rb = (lr + i) & 7;
            bf16x8 c0v = *(const bf16x8*)&krow[(((d0 >> 3)) ^ rb) * 8];
            bf16x8 c1v = *(const bf16x8*)&krow[(((d0 >> 3) + 1) ^ rb) * 8];
            #pragma unroll
            for (int j = 0; j < 8; ++j) {
                rows[i][j]     = bf2f((unsigned short)c0v[j]);
                rows[i][8 + j] = bf2f((unsigned short)c1v[j]);
            }
        }
        #pragma unroll
        for (int i = 0; i < 4; ++i) {
            float mx = -1e30f;
            #pragma unroll
            for (int j = 0; j < 16; ++j) mx = fmaxf(mx, rows[i][j]);
            mx = fmaxf(mx, __shfl_xor(mx, 1));
            mx = fmaxf(mx, __shfl_xor(mx, 2));
            mx = fmaxf(mx, __shfl_xor(mx, 4));
            float s = 0.f;
            #pragma unroll
            for (int j = 0; j < 16; ++j) { rows[i][j] = __expf(rows[i][j] - mx); s += rows[i][j]; }
            s += __shfl_xor(s, 1);
            s += __shfl_xor(s, 2);
            s += __shfl_xor(s, 4);
            const float rinv = 1.0f / s;
            #pragma unroll
            for (int j = 0; j < 16; ++j) { rows[i][j] *= rinv; ksa[j] += rows[i][j]; }
        }
        #pragma unroll
        for (int j = 0; j < 16; ++j) {
            const int d = d0 + j;
            unsigned long long pk =
                (unsigned long long)f2bf(rows[0][j]) |
                ((unsigned long long)f2bf(rows[1][j]) << 16) |
                ((unsigned long long)f2bf(rows[2][j]) << 32) |
                ((unsigned long long)f2bf(rows[3][j]) << 48);
            const int chunk = (quad >> 1) ^ (d & 7);
            *(unsigned long long*)&klT[d * DD + chunk * 8 + (quad & 1) * 4] = pk;
        }
    }
    __syncthreads();
    // ---- MFMA: A from klT LDS, B direct from global vt16 (swizzled layout) ----
    const int bkt = c * 2;
    #pragma unroll
    for (int ks = 0; ks < 4; ++ks) {
        bf16x8 af[2];
        #pragma unroll
        for (int mi = 0; mi < 2; ++mi) {
            const int d = (wid * 2 + mi) * 16 + l15;
            const int chunk = (ks * 4 + g) ^ (d & 7);
            af[mi] = *(const bf16x8*)&klT[d * DD + chunk * 8];
        }
        const int s = ks * 4 + g;
        const int kt = bkt + (s >> 3);
        #pragma unroll
        for (int nt = 0; nt < 8; ++nt) {
            const int e = nt * 16 + l15;
            const int cc = (s & 7) ^ (e & 7);
            bf16x8 bf = *(const bf16x8*)&vt16[((size_t)(h * NBLK + kt) * DD + e) * BLK + cc * 8];
            acc[0][nt] = __builtin_amdgcn_mfma_f32_16x16x32_bf16(af[0], bf, acc[0][nt], 0, 0, 0);
            acc[1][nt] = __builtin_amdgcn_mfma_f32_16x16x32_bf16(af[1], bf, acc[1][nt], 0, 0, 0);
        }
    }
    // ---- bf16 partial store (each 16-lane group writes an aligned 32B sector) ----
    unsigned short* op = kvp + (size_t)(h * NCHUNK + c) * DD * DD;
    #pragma unroll
    for (int mi = 0; mi < 2; ++mi)
        #pragma unroll
        for (int nt = 0; nt < 8; ++nt)
            #pragma unroll
            for (int r = 0; r < 4; ++r)
                op[(size_t)((wid * 2 + mi) * 16 + g * 4 + r) * DD + nt * 16 + l15] =
                    f2bf(acc[mi][nt][r]);
    #pragma unroll
    for (int j = 0; j < 16; ++j) {
        ksa[j] += __shfl_xor(ksa[j], 8);
        ksa[j] += __shfl_xor(ksa[j], 16);
        ksa[j] += __shfl_xor(ksa[j], 32);
    }
    if ((lane >> 3) == 0) {
        float* kp2 = ksp + (((size_t)h * NCHUNK + c) * 4 + wid) * DD + d0;
        #pragma unroll
        for (int j = 0; j < 16; ++j) kp2[j] = ksa[j];
    }
}

// ---------------- 3: reduce bf16 partials; Mt = (kvsum @ W^T)^T in bf16; final ksum ----------------
__global__ __launch_bounds__(256) void reduce_M(
    const unsigned short* __restrict__ kvp, const float* __restrict__ ksp,
    const float* __restrict__ W, unsigned short* __restrict__ Mt,
    float* __restrict__ ksumf)
{
    const int h = blockIdx.x, rb = blockIdx.y;
    __shared__ float kv_s[32][DD];
    const int tid = threadIdx.x;
    for (int f8 = tid; f8 < 32 * DD / 8; f8 += 256) {
        float s[8];
        #pragma unroll
        for (int j = 0; j < 8; ++j) s[j] = 0.f;
        #pragma unroll
        for (int cc = 0; cc < NCHUNK; ++cc) {
            bf16x8 x = ((const bf16x8*)(kvp + (size_t)(h * NCHUNK + cc) * DD * DD
                                        + (size_t)rb * 32 * DD))[f8];
            #pragma unroll
            for (int j = 0; j < 8; ++j) s[j] += bf2f((unsigned short)x[j]);
        }
        #pragma unroll
        for (int j = 0; j < 8; ++j) ((float*)kv_s)[f8 * 8 + j] = s[j];
    }
    if (rb == 0 && tid < DD) {
        float s = 0.f;
        #pragma unroll
        for (int p = 0; p < NCHUNK * 4; ++p)
            s += ksp[((size_t)h * NCHUNK * 4 + p) * DD + tid];
        ksumf[(size_t)h * DD + tid] = s;
    }
    __syncthreads();
    const int e = tid & 127, dh = tid >> 7;
    float accm[16];
    #pragma unroll
    for (int i = 0; i < 16; ++i) accm[i] = 0.f;
    const float4* wr4 = (const float4*)(W + (size_t)e * DD);
    for (int c4 = 0; c4 < DD / 4; ++c4) {
        const float4 wv = wr4[c4];
        #pragma unroll
        for (int i = 0; i < 16; ++i) {
            const float4 kv4 = ((const float4*)&kv_s[dh * 16 + i][0])[c4];
            accm[i] += kv4.x * wv.x + kv4.y * wv.y + kv4.z * wv.z + kv4.w * wv.w;
        }
    }
    unsigned short* mp = Mt + (size_t)h * DD * DD + (size_t)e * DD + rb * 32 + dh * 16;
    #pragma unroll
    for (int ii = 0; ii < 16; ii += 2) {
        unsigned pk = (unsigned)f2bf(accm[ii]) | ((unsigned)f2bf(accm[ii + 1]) << 16);
        *(unsigned*)&mp[ii] = pk;
    }
}

// ---------------- 4: fused sparse attention + linear epilogue (r11, known-best) ----------------
// 4 waves x 16 queries. Single-buffer K and V (40 KB LDS), 2-phase counted-vmcnt
// schedule. Single-bf16 Q. __launch_bounds__(256,3): the ONLY measured config with
// {no spill} AND {3 blocks/CU}. Spill sentinel: WRITE_SIZE == 24.58 MB.
__global__ __launch_bounds__(256, 3) void sla_attn(
    const float* __restrict__ q, const unsigned short* __restrict__ kb16,
    const unsigned short* __restrict__ vt16, const int* __restrict__ lut,
    const unsigned short* __restrict__ Mt, const float* __restrict__ ksumf,
    const float* __restrict__ pb, float* __restrict__ out)
{
    const int b = blockIdx.x;
    const int slot = b >> 3;
    const int h = (b & 7) + 8 * (slot >> 5);
    const int nq = slot & 31;

    __shared__ unsigned short Ks[BLK * DD];      // 16 KB, K[it]
    __shared__ unsigned short Vt[DD * BLK];      // 16 KB, V[it]
    __shared__ unsigned short Ps[4 * 16 * BLK];  // 8 KB  -> 40 KB total

    const int tid = threadIdx.x;
    const int wid = tid >> 6, lane = tid & 63;
    const int l15 = lane & 15, g = lane >> 4;
    const int q0 = wid * 16;

    // ---- Q fragments: scale folded, single bf16, stationary ----
    bf16x8 qf[4];
    {
        const float scale = 0.08838834764831845f;
        const int qrow = nq * BLK + q0 + l15;
        const float* qp = q + ((size_t)qrow * HH + h) * DD;
        #pragma unroll
        for (int ks = 0; ks < 4; ++ks) {
            const int d0 = ks * 32 + g * 8;
            float4 a = *(const float4*)(qp + d0);
            float4 c = *(const float4*)(qp + d0 + 4);
            float vv[8] = {a.x, a.y, a.z, a.w, c.x, c.y, c.z, c.w};
            #pragma unroll
            for (int j = 0; j < 8; ++j)
                qf[ks][j] = (short)f2bf(vv[j] * scale);
        }
    }

    f32x4 Oacc[8];
    #pragma unroll
    for (int nt = 0; nt < 8; ++nt) Oacc[nt] = (f32x4){0.f, 0.f, 0.f, 0.f};
    float m_run = -1e30f, l_run = 0.f;

    const int* lrow = lut + ((size_t)h * NBLK + nq) * TOPK;

    // prologue: issue K[0] (wave w stages slices 4w..4w+3, 1 KB each)
    {
        const int kb0 = lrow[0];
        const unsigned short* kg = kb16 + ((size_t)h * LLEN + (size_t)kb0 * BLK) * DD;
        #pragma unroll
        for (int i = 0; i < 4; ++i) {
            const int is = wid * 4 + i;
            gload16(&Ks[is * 512], kg + is * 512 + lane * 8);
        }
    }

    for (int it = 0; it < TOPK; ++it) {
        const int kbI = lrow[it];
        __builtin_amdgcn_s_barrier();   // prev iter's V/Ps readers done
        // ---- stage V[it]; outstanding: K[it](4) + V[it](4) ----
        {
            const unsigned short* vg = vt16 + (size_t)(h * NBLK + kbI) * DD * BLK;
            #pragma unroll
            for (int i = 0; i < 4; ++i) {
                const int is = wid * 4 + i;
                gload16(&Vt[is * 512], vg + is * 512 + lane * 8);
            }
        }
        asm volatile("s_waitcnt vmcnt(4)" ::: "memory");  // K[it] landed; V still in flight
        __builtin_amdgcn_sched_barrier(0);

        // ---- S^T = K . Q^T (16 MFMA) ----
        f32x4 sacc[4];
        #pragma unroll
        for (int mt = 0; mt < 4; ++mt) sacc[mt] = (f32x4){0.f, 0.f, 0.f, 0.f};
        __builtin_amdgcn_s_setprio(1);
        #pragma unroll
        for (int ks = 0; ks < 4; ++ks) {
            #pragma unroll
            for (int mt = 0; mt < 4; ++mt) {
                const int row = mt * 16 + l15;
                const int chunk = (ks * 4 + g) ^ (row & 7);
                bf16x8 kf = *(const bf16x8*)&Ks[row * DD + chunk * 8];
                sacc[mt] = __builtin_amdgcn_mfma_f32_16x16x32_bf16(kf, qf[ks], sacc[mt], 0, 0, 0);
            }
        }
        __builtin_amdgcn_s_setprio(0);

        __builtin_amdgcn_s_barrier();   // all waves consumed K[it]
        // ---- prefetch K[it+1]; spans softmax + PV + next top barrier ----
        if (it + 1 < TOPK) {
            const int kbN = lrow[it + 1];
            const unsigned short* kg = kb16 + ((size_t)h * LLEN + (size_t)kbN * BLK) * DD;
            #pragma unroll
            for (int i = 0; i < 4; ++i) {
                const int is = wid * 4 + i;
                gload16(&Ks[is * 512], kg + is * 512 + lane * 8);
            }
        }

        // ---- online softmax ----
        float sv[16];
        #pragma unroll
        for (int mt = 0; mt < 4; ++mt)
            #pragma unroll
            for (int r = 0; r < 4; ++r) sv[mt * 4 + r] = sacc[mt][r];
        float mx = -1e30f;
        #pragma unroll
        for (int i = 0; i < 16; ++i) mx = fmaxf(mx, sv[i]);
        mx = fmaxf(mx, __shfl_xor(mx, 16));
        mx = fmaxf(mx, __shfl_xor(mx, 32));
        const float mnew = fmaxf(m_run, mx);
        const float alpha = __expf(m_run - mnew);
        float ssum = 0.f;
        #pragma unroll
        for (int i = 0; i < 16; ++i) { sv[i] = __expf(sv[i] - mnew); ssum += sv[i]; }
        ssum += __shfl_xor(ssum, 16);
        ssum += __shfl_xor(ssum, 32);
        l_run = l_run * alpha + ssum;
        m_run = mnew;

        // ---- P to LDS (own-wave region; in-wave ordering) ----
        {
            unsigned short* pw = Ps + wid * (16 * BLK) + l15 * BLK;
            #pragma unroll
            for (int mt = 0; mt < 4; ++mt) {
                #pragma unroll
                for (int pr = 0; pr < 2; ++pr) {
                    const int key = mt * 16 + g * 4 + pr * 2;
                    unsigned pak = (unsigned)f2bf(sv[mt * 4 + pr * 2])
                                 | ((unsigned)f2bf(sv[mt * 4 + pr * 2 + 1]) << 16);
                    const int chunk = (key >> 3) ^ (l15 & 7);
                    *(unsigned*)&pw[chunk * 8 + (key & 7)] = pak;
                }
            }
        }

        // ---- V[it] landed? (oldest 4 = V; K[it+1] stays in flight) ----
        if (it + 1 < TOPK) {
            asm volatile("s_waitcnt vmcnt(4)" ::: "memory");
        } else {
            asm volatile("s_waitcnt vmcnt(0)" ::: "memory");
        }
        __builtin_amdgcn_sched_barrier(0);

        // ---- O rescale + PV ----
        {
            float ar[4];
            #pragma unroll
            for (int r = 0; r < 4; ++r) ar[r] = __shfl(alpha, g * 4 + r);
            #pragma unroll
            for (int nt = 0; nt < 8; ++nt) {
                Oacc[nt][0] *= ar[0]; Oacc[nt][1] *= ar[1];
                Oacc[nt][2] *= ar[2]; Oacc[nt][3] *= ar[3];
            }
            const unsigned short* prd = Ps + wid * (16 * BLK) + l15 * BLK;
            #pragma unroll
            for (int ks2 = 0; ks2 < 2; ++ks2) {
                const int pch = (g + 4 * ks2) ^ (l15 & 7);
                bf16x8 pa = *(const bf16x8*)&prd[pch * 8];
                __builtin_amdgcn_s_setprio(1);
                #pragma unroll
                for (int nt = 0; nt < 8; ++nt) {
                    const int drow = nt * 16 + l15;
                    const int vch = (g + 4 * ks2) ^ (drow & 7);
                    bf16x8 vf = *(const bf16x8*)&Vt[drow * BLK + vch * 8];
                    Oacc[nt] = __builtin_amdgcn_mfma_f32_16x16x32_bf16(pa, vf, Oacc[nt], 0, 0, 0);
                }
                __builtin_amdgcn_s_setprio(0);
            }
        }
    }

    // ---- fused linear-attn epilogue: ql softmax + 32 MFMAs vs Mt (L2-hot global) ----
    float qv[32];
    {
        const float iscale = 11.313708498984761f;  // sqrt(D): undo folded scale
        #pragma unroll
        for (int ks = 0; ks < 4; ++ks)
            #pragma unroll
            for (int j = 0; j < 8; ++j)
                qv[ks * 8 + j] = bf2f((unsigned short)qf[ks][j]) * iscale;
    }
    float mx2 = -1e30f;
    #pragma unroll
    for (int j = 0; j < 32; ++j) mx2 = fmaxf(mx2, qv[j]);
    mx2 = fmaxf(mx2, __shfl_xor(mx2, 16));
    mx2 = fmaxf(mx2, __shfl_xor(mx2, 32));
    float s2 = 0.f;
    #pragma unroll
    for (int j = 0; j < 32; ++j) { qv[j] = __expf(qv[j] - mx2); s2 += qv[j]; }
    s2 += __shfl_xor(s2, 16);
    s2 += __shfl_xor(s2, 32);
    const float rinv = 1.0f / s2;
    float den = 0.f;
    bf16x8 af[4];
    {
        const float* ksb = ksumf + (size_t)h * DD;
        #pragma unroll
        for (int ks = 0; ks < 4; ++ks) {
            const int dd0 = ks * 32 + g * 8;
            float4 k0 = *(const float4*)(ksb + dd0);
            float4 k1 = *(const float4*)(ksb + dd0 + 4);
            float kk[8] = {k0.x, k0.y, k0.z, k0.w, k1.x, k1.y, k1.z, k1.w};
            #pragma unroll
            for (int j = 0; j < 8; ++j) {
                const float ql = qv[ks * 8 + j] * rinv;
                af[ks][j] = (short)f2bf(ql);
                den += ql * kk[j];
            }
        }
    }
    den += __shfl_xor(den, 16);
    den += __shfl_xor(den, 32);
    const float dinv = 1.0f / (1e-5f + den);

    f32x4 acc2[8];
    #pragma unroll
    for (int nt = 0; nt < 8; ++nt) acc2[nt] = (f32x4){0.f, 0.f, 0.f, 0.f};
    {
        const unsigned short* mrow = Mt + (size_t)h * DD * DD;
        #pragma unroll
        for (int ks = 0; ks < 4; ++ks) {
            #pragma unroll
            for (int nt = 0; nt < 8; ++nt) {
                bf16x8 bf = *(const bf16x8*)&mrow[(size_t)(nt * 16 + l15) * DD + (ks * 4 + g) * 8];
                acc2[nt] = __builtin_amdgcn_mfma_f32_16x16x32_bf16(af[ks], bf, acc2[nt], 0, 0, 0);
            }
        }
    }

    // ---- combine + bias, single store ----
    float bias[8];
    #pragma unroll
    for (int nt = 0; nt < 8; ++nt) bias[nt] = pb[nt * 16 + l15];
    #pragma unroll
    for (int r = 0; r < 4; ++r) {
        const float linv = 1.0f / __shfl(l_run, g * 4 + r);
        const float di = __shfl(dinv, g * 4 + r);
        const int grow = nq * BLK + q0 + g * 4 + r;
        float* dst = out + ((size_t)grow * HH + h) * DD + l15;
        #pragma unroll
        for (int nt = 0; nt < 8; ++nt)
            dst[nt * 16] = Oacc[nt][r] * linv + acc2[nt][r] * di + bias[nt];
    }
}

extern "C" void kernel_launch(void* const* d_in, const int* in_sizes, int n_in,
                              void* d_out, int out_size, void* d_ws, size_t ws_size,
                              hipStream_t stream)
{
    (void)in_sizes; (void)n_in; (void)out_size; (void)ws_size;
    const float* q  = (const float*)d_in[0];
    const float* k  = (const float*)d_in[1];
    const float* v  = (const float*)d_in[2];
    const float* pw = (const float*)d_in[3];
    const float* pb = (const float*)d_in[4];
    float* out = (float*)d_out;
    char* ws = (char*)d_ws;
    size_t off = 0;
    int*   lut   = (int*)(ws + off);   off += (size_t)HH * NBLK * TOPK * 4;
    float* qb    = (float*)(ws + off); off += (size_t)HH * NBLK * DD * 4;
    float* kb    = (float*)(ws + off); off += (size_t)HH * NBLK * DD * 4;
    unsigned short* kvp = (unsigned short*)(ws + off); off += (size_t)HH * NCHUNK * DD * DD * 2;
    float* ksp   = (float*)(ws + off); off += (size_t)HH * NCHUNK * 4 * DD * 4;
    unsigned short* Mt = (unsigned short*)(ws + off); off += (size_t)HH * DD * DD * 2;
    float* ksumf = (float*)(ws + off); off += (size_t)HH * DD * 4;
    unsigned short* kb16 = (unsigned short*)(ws + off); off += (size_t)HH * LLEN * DD * 2;
    unsigned short* vt16 = (unsigned short*)(ws + off); off += (size_t)HH * LLEN * DD * 2;

    convert_pool<<<dim3(NBLK, HH), 256, 0, stream>>>(q, k, v, kb16, vt16, qb, kb);
    topk_kernel<<<HH, 256, 0, stream>>>(qb, kb, lut);
    kv_mfma<<<dim3(HH, NCHUNK), 256, 0, stream>>>(kb16, vt16, kvp, ksp);
    reduce_M<<<dim3(HH, 4), 256, 0, stream>>>(kvp, ksp, pw, Mt, ksumf);
    sla_attn<<<NBLK * HH, 256, 0, stream>>>(q, kb16, vt16, lut, Mt, ksumf, pb, out);
}

// Round 17
// 131.111 us; speedup vs baseline: 1.0419x; 1.0419x over previous
//
#include <hip/hip_runtime.h>
#include <math.h>

#define HH 24
#define LLEN 2048
#define DD 128
#define BLK 64
#define NBLK 32
#define TOPK 16
#define NCHUNK 16

typedef __attribute__((ext_vector_type(8))) short bf16x8;
typedef __attribute__((ext_vector_type(4))) float f32x4;

typedef unsigned int u32_g __attribute__((address_space(1)));
typedef unsigned int u32_l __attribute__((address_space(3)));

__device__ __forceinline__ unsigned short f2bf(float f) {
    unsigned u = __builtin_bit_cast(unsigned, f);
    unsigned r = (u + 0x7FFFu + ((u >> 16) & 1u)) >> 16;
    return (unsigned short)r;
}
__device__ __forceinline__ float bf2f(unsigned short b) {
    unsigned u = ((unsigned)b) << 16;
    return __builtin_bit_cast(float, u);
}
// async 16B/lane global->LDS: lds base is WAVE-UNIFORM (lane0); HW adds lane*16.
__device__ __forceinline__ void gload16(unsigned short* lds, const unsigned short* g) {
    __builtin_amdgcn_global_load_lds((const u32_g*)g, (u32_l*)lds, 16, 0, 0);
}

// ---------------- 1: convert K/V to bf16 (pre-swizzled) + block pooling (r11) ----------------
// kb16[h][l][chunk^(l&7)] row-major bf16; vt16[h][ktile][d][keychunk^(d&7)] transposed bf16.
__global__ __launch_bounds__(256) void convert_pool(
    const float* __restrict__ q, const float* __restrict__ k, const float* __restrict__ v,
    unsigned short* __restrict__ kb16, unsigned short* __restrict__ vt16,
    float* __restrict__ qb, float* __restrict__ kb)
{
    const int nb = blockIdx.x, h = blockIdx.y;
    const int l0 = nb * BLK;
    const int tid = threadIdx.x;
    __shared__ unsigned short vt_s[DD * BLK];  // 16 KB

    // ---- K convert: swizzled row writes ----
    {
        const int r = tid >> 2, c0 = (tid & 3) * 4;
        const float* kp = k + ((size_t)(l0 + r) * HH + h) * DD + c0 * 8;
        unsigned short* krow = kb16 + ((size_t)h * LLEN + l0 + r) * DD;
        #pragma unroll
        for (int j = 0; j < 4; ++j) {
            float4 a = *(const float4*)(kp + j * 8);
            float4 c = *(const float4*)(kp + j * 8 + 4);
            unsigned short tmp[8] = {f2bf(a.x), f2bf(a.y), f2bf(a.z), f2bf(a.w),
                                     f2bf(c.x), f2bf(c.y), f2bf(c.z), f2bf(c.w)};
            const int chunk = (c0 + j) ^ (r & 7);
            *(bf16x8*)&krow[chunk * 8] = *(bf16x8*)tmp;
        }
    }
    // ---- V transpose via LDS bounce (packed key-pair u32 writes, swizzled) ----
    {
        const int kp2 = tid >> 3, dgb = tid & 7;
        const float* v0p = v + ((size_t)(l0 + kp2 * 2) * HH + h) * DD;
        const float* v1p = v0p + (size_t)HH * DD;
        #pragma unroll
        for (int j2 = 0; j2 < 4; ++j2) {
            const int d0 = dgb * 4 + j2 * 32;
            float4 a = *(const float4*)(v0p + d0);
            float4 c = *(const float4*)(v1p + d0);
            float a4[4] = {a.x, a.y, a.z, a.w}, c4[4] = {c.x, c.y, c.z, c.w};
            #pragma unroll
            for (int i = 0; i < 4; ++i) {
                unsigned pak = (unsigned)f2bf(a4[i]) | ((unsigned)f2bf(c4[i]) << 16);
                const int d = d0 + i;
                const int chunk = (kp2 >> 2) ^ (d & 7);
                *(unsigned*)&vt_s[d * BLK + chunk * 8 + (kp2 & 3) * 2] = pak;
            }
        }
    }
    __syncthreads();
    // copy-out keeps the swizzle: LDS stage in sla_attn is a linear copy (rule #21)
    {
        bf16x8* dstv = (bf16x8*)(vt16 + (size_t)(h * NBLK + nb) * DD * BLK);
        const bf16x8* srcv = (const bf16x8*)vt_s;
        #pragma unroll
        for (int j = 0; j < 4; ++j) dstv[tid * 4 + j] = srcv[tid * 4 + j];
    }
    __syncthreads();
    // ---- block-sum pooling (L1-hot re-read) ----
    {
        float* ps = (float*)vt_s;
        const int d = tid & 127, half = tid >> 7;
        const size_t rs = (size_t)HH * DD;
        const float* qp = q + ((size_t)(l0 + half * 32) * HH + h) * DD + d;
        const float* kp = k + ((size_t)(l0 + half * 32) * HH + h) * DD + d;
        float sq = 0.f, sk = 0.f;
        #pragma unroll 8
        for (int i = 0; i < 32; ++i) { sq += qp[i * rs]; sk += kp[i * rs]; }
        ps[half * 128 + d] = sq;
        ps[256 + half * 128 + d] = sk;
        __syncthreads();
        if (half == 0) {
            qb[((size_t)h * NBLK + nb) * DD + d] = ps[d] + ps[128 + d];
            kb[((size_t)h * NBLK + nb) * DD + d] = ps[256 + d] + ps[384 + d];
        }
    }
}

// ---------------- 2: FUSED kvsum-partials GEMM + topk ----------------
// 1D grid: blocks [0, HH*NCHUNK) do the kv MFMA partial; blocks [HH*NCHUNK, +HH) do
// the per-head top-16 LUT (24 blocks that previously occupied a whole serialized
// dispatch while using 24/256 CUs). Both read only convert_pool outputs -> independent.
__global__ __launch_bounds__(256, 2) void kv_topk(
    const unsigned short* __restrict__ kb16, const unsigned short* __restrict__ vt16,
    unsigned short* __restrict__ kvp, float* __restrict__ ksp,
    const float* __restrict__ qb, const float* __restrict__ kb, int* __restrict__ lut)
{
    __shared__ unsigned short smem[DD * DD];  // 32 KB, aliased by both paths
    const int bid = blockIdx.x;
    const int tid = threadIdx.x;

    if (bid < HH * NCHUNK) {
        // ================= kv partial: klT . V over 128 rows =================
        const int h = bid >> 4, c = bid & 15;
        unsigned short* klT = smem;  // [d][l] swizzled, 32 KB
        const int quad = tid >> 3, dpart = tid & 7;
        const int d0 = dpart * 16;
        const int wid = tid >> 6, lane = tid & 63;
        const int l15 = lane & 15, g = lane >> 4;

        f32x4 acc[2][8];
        #pragma unroll
        for (int mi = 0; mi < 2; ++mi)
            #pragma unroll
            for (int nt = 0; nt < 8; ++nt) acc[mi][nt] = (f32x4){0.f, 0.f, 0.f, 0.f};
        float ksa[16];
        #pragma unroll
        for (int j = 0; j < 16; ++j) ksa[j] = 0.f;

        const int l0 = c * DD;
        {
            const int lr = quad * 4;
            float rows[4][16];
            // read K from kb16 (swizzled row chunks: pos = chunk ^ (l&7))
            #pragma unroll
            for (int i = 0; i < 4; ++i) {
                const unsigned short* krow = kb16 + ((size_t)h * LLEN + l0 + lr + i) * DD;
                const int rb = (lr + i) & 7;
                bf16x8 c0v = *(const bf16x8*)&krow[(((d0 >> 3)) ^ rb) * 8];
                bf16x8 c1v = *(const bf16x8*)&krow[(((d0 >> 3) + 1) ^ rb) * 8];
                #pragma unroll
                for (int j = 0; j < 8; ++j) {
                    rows[i][j]     = bf2f((unsigned short)c0v[j]);
                    rows[i][8 + j] = bf2f((unsigned short)c1v[j]);
                }
            }
            #pragma unroll
            for (int i = 0; i < 4; ++i) {
                float mx = -1e30f;
                #pragma unroll
                for (int j = 0; j < 16; ++j) mx = fmaxf(mx, rows[i][j]);
                mx = fmaxf(mx, __shfl_xor(mx, 1));
                mx = fmaxf(mx, __shfl_xor(mx, 2));
                mx = fmaxf(mx, __shfl_xor(mx, 4));
                float s = 0.f;
                #pragma unroll
                for (int j = 0; j < 16; ++j) { rows[i][j] = __expf(rows[i][j] - mx); s += rows[i][j]; }
                s += __shfl_xor(s, 1);
                s += __shfl_xor(s, 2);
                s += __shfl_xor(s, 4);
                const float rinv = 1.0f / s;
                #pragma unroll
                for (int j = 0; j < 16; ++j) { rows[i][j] *= rinv; ksa[j] += rows[i][j]; }
            }
            #pragma unroll
            for (int j = 0; j < 16; ++j) {
                const int d = d0 + j;
                unsigned long long pk =
                    (unsigned long long)f2bf(rows[0][j]) |
                    ((unsigned long long)f2bf(rows[1][j]) << 16) |
                    ((unsigned long long)f2bf(rows[2][j]) << 32) |
                    ((unsigned long long)f2bf(rows[3][j]) << 48);
                const int chunk = (quad >> 1) ^ (d & 7);
                *(unsigned long long*)&klT[d * DD + chunk * 8 + (quad & 1) * 4] = pk;
            }
        }
        __syncthreads();
        const int bkt = c * 2;
        #pragma unroll
        for (int ks = 0; ks < 4; ++ks) {
            bf16x8 af[2];
            #pragma unroll
            for (int mi = 0; mi < 2; ++mi) {
                const int d = (wid * 2 + mi) * 16 + l15;
                const int chunk = (ks * 4 + g) ^ (d & 7);
                af[mi] = *(const bf16x8*)&klT[d * DD + chunk * 8];
            }
            const int s = ks * 4 + g;
            const int kt = bkt + (s >> 3);
            #pragma unroll
            for (int nt = 0; nt < 8; ++nt) {
                const int e = nt * 16 + l15;
                const int cc = (s & 7) ^ (e & 7);
                bf16x8 bf = *(const bf16x8*)&vt16[((size_t)(h * NBLK + kt) * DD + e) * BLK + cc * 8];
                acc[0][nt] = __builtin_amdgcn_mfma_f32_16x16x32_bf16(af[0], bf, acc[0][nt], 0, 0, 0);
                acc[1][nt] = __builtin_amdgcn_mfma_f32_16x16x32_bf16(af[1], bf, acc[1][nt], 0, 0, 0);
            }
        }
        unsigned short* op = kvp + (size_t)(h * NCHUNK + c) * DD * DD;
        #pragma unroll
        for (int mi = 0; mi < 2; ++mi)
            #pragma unroll
            for (int nt = 0; nt < 8; ++nt)
                #pragma unroll
                for (int r = 0; r < 4; ++r)
                    op[(size_t)((wid * 2 + mi) * 16 + g * 4 + r) * DD + nt * 16 + l15] =
                        f2bf(acc[mi][nt][r]);
        #pragma unroll
        for (int j = 0; j < 16; ++j) {
            ksa[j] += __shfl_xor(ksa[j], 8);
            ksa[j] += __shfl_xor(ksa[j], 16);
            ksa[j] += __shfl_xor(ksa[j], 32);
        }
        if ((lane >> 3) == 0) {
            float* kp2 = ksp + (((size_t)h * NCHUNK + c) * 4 + wid) * DD + d0;
            #pragma unroll
            for (int j = 0; j < 16; ++j) kp2[j] = ksa[j];
        }
    } else {
        // ================= topk: block scores + top-16 LUT =================
        const int h = bid - HH * NCHUNK;
        float* kb_s = (float*)smem;                       // [NBLK][DD], 16 KB
        float* sc = (float*)(smem + NBLK * DD * 2);       // [NBLK][NBLK], 4 KB
        for (int f = tid; f < NBLK * DD / 4; f += 256)
            ((float4*)kb_s)[f] = ((const float4*)(kb + (size_t)h * NBLK * DD))[f];
        __syncthreads();
        for (int p = tid; p < NBLK * NBLK; p += 256) {
            const int iq = p >> 5, ik = p & 31;
            const float4* qr4 = (const float4*)(qb + ((size_t)h * NBLK + iq) * DD);
            const float4* kr4 = (const float4*)&kb_s[ik * DD];
            float s = 0.f;
            for (int dq = 0; dq < DD / 4; ++dq) {
                float4 a = qr4[dq], b = kr4[dq];
                s += a.x * b.x + a.y * b.y + a.z * b.z + a.w * b.w;
            }
            sc[iq * NBLK + ik] = s;
        }
        __syncthreads();
        if (tid < NBLK) {
            const int iq = tid;
            for (int t = 0; t < TOPK; ++t) {
                float bv = -1e30f; int bi = 0;
                for (int j = 0; j < NBLK; ++j) {
                    float s = sc[iq * NBLK + j];
                    if (s > bv) { bv = s; bi = j; }
                }
                lut[((size_t)h * NBLK + iq) * TOPK + t] = bi;
                sc[iq * NBLK + bi] = -1e30f;
            }
        }
    }
}

// ---------------- 3: reduce bf16 partials; Mt = (kvsum @ W^T)^T in bf16; final ksum ----------------
__global__ __launch_bounds__(256) void reduce_M(
    const unsigned short* __restrict__ kvp, const float* __restrict__ ksp,
    const float* __restrict__ W, unsigned short* __restrict__ Mt,
    float* __restrict__ ksumf)
{
    const int h = blockIdx.x, rb = blockIdx.y;
    __shared__ float kv_s[32][DD];
    const int tid = threadIdx.x;
    for (int f8 = tid; f8 < 32 * DD / 8; f8 += 256) {
        float s[8];
        #pragma unroll
        for (int j = 0; j < 8; ++j) s[j] = 0.f;
        #pragma unroll
        for (int cc = 0; cc < NCHUNK; ++cc) {
            bf16x8 x = ((const bf16x8*)(kvp + (size_t)(h * NCHUNK + cc) * DD * DD
                                        + (size_t)rb * 32 * DD))[f8];
            #pragma unroll
            for (int j = 0; j < 8; ++j) s[j] += bf2f((unsigned short)x[j]);
        }
        #pragma unroll
        for (int j = 0; j < 8; ++j) ((float*)kv_s)[f8 * 8 + j] = s[j];
    }
    if (rb == 0 && tid < DD) {
        float s = 0.f;
        #pragma unroll
        for (int p = 0; p < NCHUNK * 4; ++p)
            s += ksp[((size_t)h * NCHUNK * 4 + p) * DD + tid];
        ksumf[(size_t)h * DD + tid] = s;
    }
    __syncthreads();
    const int e = tid & 127, dh = tid >> 7;
    float accm[16];
    #pragma unroll
    for (int i = 0; i < 16; ++i) accm[i] = 0.f;
    const float4* wr4 = (const float4*)(W + (size_t)e * DD);
    for (int c4 = 0; c4 < DD / 4; ++c4) {
        const float4 wv = wr4[c4];
        #pragma unroll
        for (int i = 0; i < 16; ++i) {
            const float4 kv4 = ((const float4*)&kv_s[dh * 16 + i][0])[c4];
            accm[i] += kv4.x * wv.x + kv4.y * wv.y + kv4.z * wv.z + kv4.w * wv.w;
        }
    }
    unsigned short* mp = Mt + (size_t)h * DD * DD + (size_t)e * DD + rb * 32 + dh * 16;
    #pragma unroll
    for (int ii = 0; ii < 16; ii += 2) {
        unsigned pk = (unsigned)f2bf(accm[ii]) | ((unsigned)f2bf(accm[ii + 1]) << 16);
        *(unsigned*)&mp[ii] = pk;
    }
}

// ---------------- 4: fused sparse attention + linear epilogue (r11 + defer-max) ----------------
// 4 waves x 16 queries, 40 KB LDS, counted-vmcnt 2-phase, (256,3) — the proven config.
// NEW: T13 defer-max — skip O-rescale + alpha when the tile max doesn't grow by >8
// (wave-uniform vote); P bounded by e^8, bf16/f32 relative precision unaffected.
// Spill sentinel: WRITE_SIZE == 24.58 MB.
__global__ __launch_bounds__(256, 3) void sla_attn(
    const float* __restrict__ q, const unsigned short* __restrict__ kb16,
    const unsigned short* __restrict__ vt16, const int* __restrict__ lut,
    const unsigned short* __restrict__ Mt, const float* __restrict__ ksumf,
    const float* __restrict__ pb, float* __restrict__ out)
{
    const int b = blockIdx.x;
    const int slot = b >> 3;
    const int h = (b & 7) + 8 * (slot >> 5);
    const int nq = slot & 31;

    __shared__ unsigned short Ks[BLK * DD];      // 16 KB, K[it]
    __shared__ unsigned short Vt[DD * BLK];      // 16 KB, V[it]
    __shared__ unsigned short Ps[4 * 16 * BLK];  // 8 KB  -> 40 KB total

    const int tid = threadIdx.x;
    const int wid = tid >> 6, lane = tid & 63;
    const int l15 = lane & 15, g = lane >> 4;
    const int q0 = wid * 16;

    // ---- Q fragments: scale folded, single bf16, stationary ----
    bf16x8 qf[4];
    {
        const float scale = 0.08838834764831845f;
        const int qrow = nq * BLK + q0 + l15;
        const float* qp = q + ((size_t)qrow * HH + h) * DD;
        #pragma unroll
        for (int ks = 0; ks < 4; ++ks) {
            const int d0 = ks * 32 + g * 8;
            float4 a = *(const float4*)(qp + d0);
            float4 c = *(const float4*)(qp + d0 + 4);
            float vv[8] = {a.x, a.y, a.z, a.w, c.x, c.y, c.z, c.w};
            #pragma unroll
            for (int j = 0; j < 8; ++j)
                qf[ks][j] = (short)f2bf(vv[j] * scale);
        }
    }

    f32x4 Oacc[8];
    #pragma unroll
    for (int nt = 0; nt < 8; ++nt) Oacc[nt] = (f32x4){0.f, 0.f, 0.f, 0.f};
    float m_run = -1e30f, l_run = 0.f;

    const int* lrow = lut + ((size_t)h * NBLK + nq) * TOPK;

    // prologue: issue K[0] (wave w stages slices 4w..4w+3, 1 KB each)
    {
        const int kb0 = lrow[0];
        const unsigned short* kg = kb16 + ((size_t)h * LLEN + (size_t)kb0 * BLK) * DD;
        #pragma unroll
        for (int i = 0; i < 4; ++i) {
            const int is = wid * 4 + i;
            gload16(&Ks[is * 512], kg + is * 512 + lane * 8);
        }
    }

    for (int it = 0; it < TOPK; ++it) {
        const int kbI = lrow[it];
        __builtin_amdgcn_s_barrier();   // prev iter's V/Ps readers done
        // ---- stage V[it]; outstanding: K[it](4) + V[it](4) ----
        {
            const unsigned short* vg = vt16 + (size_t)(h * NBLK + kbI) * DD * BLK;
            #pragma unroll
            for (int i = 0; i < 4; ++i) {
                const int is = wid * 4 + i;
                gload16(&Vt[is * 512], vg + is * 512 + lane * 8);
            }
        }
        asm volatile("s_waitcnt vmcnt(4)" ::: "memory");  // K[it] landed; V still in flight
        __builtin_amdgcn_sched_barrier(0);

        // ---- S^T = K . Q^T (16 MFMA) ----
        f32x4 sacc[4];
        #pragma unroll
        for (int mt = 0; mt < 4; ++mt) sacc[mt] = (f32x4){0.f, 0.f, 0.f, 0.f};
        __builtin_amdgcn_s_setprio(1);
        #pragma unroll
        for (int ks = 0; ks < 4; ++ks) {
            #pragma unroll
            for (int mt = 0; mt < 4; ++mt) {
                const int row = mt * 16 + l15;
                const int chunk = (ks * 4 + g) ^ (row & 7);
                bf16x8 kf = *(const bf16x8*)&Ks[row * DD + chunk * 8];
                sacc[mt] = __builtin_amdgcn_mfma_f32_16x16x32_bf16(kf, qf[ks], sacc[mt], 0, 0, 0);
            }
        }
        __builtin_amdgcn_s_setprio(0);

        __builtin_amdgcn_s_barrier();   // all waves consumed K[it]
        // ---- prefetch K[it+1]; spans softmax + PV + next top barrier ----
        if (it + 1 < TOPK) {
            const int kbN = lrow[it + 1];
            const unsigned short* kg = kb16 + ((size_t)h * LLEN + (size_t)kbN * BLK) * DD;
            #pragma unroll
            for (int i = 0; i < 4; ++i) {
                const int is = wid * 4 + i;
                gload16(&Ks[is * 512], kg + is * 512 + lane * 8);
            }
        }

        // ---- online softmax with defer-max (T13) ----
        float sv[16];
        #pragma unroll
        for (int mt = 0; mt < 4; ++mt)
            #pragma unroll
            for (int r = 0; r < 4; ++r) sv[mt * 4 + r] = sacc[mt][r];
        float mx = -1e30f;
        #pragma unroll
        for (int i = 0; i < 16; ++i) mx = fmaxf(mx, sv[i]);
        mx = fmaxf(mx, __shfl_xor(mx, 16));
        mx = fmaxf(mx, __shfl_xor(mx, 32));
        const bool need = __any(mx > m_run + 8.0f) != 0;   // wave-uniform
        const float mnew = need ? fmaxf(m_run, mx) : m_run;
        float ssum = 0.f;
        #pragma unroll
        for (int i = 0; i < 16; ++i) { sv[i] = __expf(sv[i] - mnew); ssum += sv[i]; }
        ssum += __shfl_xor(ssum, 16);
        ssum += __shfl_xor(ssum, 32);
        float alpha = 1.0f;
        if (need) alpha = __expf(m_run - mnew);
        l_run = l_run * alpha + ssum;
        m_run = mnew;

        // ---- P to LDS (own-wave region; in-wave ordering) ----
        {
            unsigned short* pw = Ps + wid * (16 * BLK) + l15 * BLK;
            #pragma unroll
            for (int mt = 0; mt < 4; ++mt) {
                #pragma unroll
                for (int pr = 0; pr < 2; ++pr) {
                    const int key = mt * 16 + g * 4 + pr * 2;
                    unsigned pak = (unsigned)f2bf(sv[mt * 4 + pr * 2])
                                 | ((unsigned)f2bf(sv[mt * 4 + pr * 2 + 1]) << 16);
                    const int chunk = (key >> 3) ^ (l15 & 7);
                    *(unsigned*)&pw[chunk * 8 + (key & 7)] = pak;
                }
            }
        }

        // ---- V[it] landed? (oldest 4 = V; K[it+1] stays in flight) ----
        if (it + 1 < TOPK) {
            asm volatile("s_waitcnt vmcnt(4)" ::: "memory");
        } else {
            asm volatile("s_waitcnt vmcnt(0)" ::: "memory");
        }
        __builtin_amdgcn_sched_barrier(0);

        // ---- O rescale (skipped when deferred) + PV ----
        {
            if (need) {
                float ar[4];
                #pragma unroll
                for (int r = 0; r < 4; ++r) ar[r] = __shfl(alpha, g * 4 + r);
                #pragma unroll
                for (int nt = 0; nt < 8; ++nt) {
                    Oacc[nt][0] *= ar[0]; Oacc[nt][1] *= ar[1];
                    Oacc[nt][2] *= ar[2]; Oacc[nt][3] *= ar[3];
                }
            }
            const unsigned short* prd = Ps + wid * (16 * BLK) + l15 * BLK;
            #pragma unroll
            for (int ks2 = 0; ks2 < 2; ++ks2) {
                const int pch = (g + 4 * ks2) ^ (l15 & 7);
                bf16x8 pa = *(const bf16x8*)&prd[pch * 8];
                __builtin_amdgcn_s_setprio(1);
                #pragma unroll
                for (int nt = 0; nt < 8; ++nt) {
                    const int drow = nt * 16 + l15;
                    const int vch = (g + 4 * ks2) ^ (drow & 7);
                    bf16x8 vf = *(const bf16x8*)&Vt[drow * BLK + vch * 8];
                    Oacc[nt] = __builtin_amdgcn_mfma_f32_16x16x32_bf16(pa, vf, Oacc[nt], 0, 0, 0);
                }
                __builtin_amdgcn_s_setprio(0);
            }
        }
    }

    // ---- fused linear-attn epilogue: ql softmax + 32 MFMAs vs Mt (L2-hot global) ----
    float qv[32];
    {
        const float iscale = 11.313708498984761f;  // sqrt(D): undo folded scale
        #pragma unroll
        for (int ks = 0; ks < 4; ++ks)
            #pragma unroll
            for (int j = 0; j < 8; ++j)
                qv[ks * 8 + j] = bf2f((unsigned short)qf[ks][j]) * iscale;
    }
    float mx2 = -1e30f;
    #pragma unroll
    for (int j = 0; j < 32; ++j) mx2 = fmaxf(mx2, qv[j]);
    mx2 = fmaxf(mx2, __shfl_xor(mx2, 16));
    mx2 = fmaxf(mx2, __shfl_xor(mx2, 32));
    float s2 = 0.f;
    #pragma unroll
    for (int j = 0; j < 32; ++j) { qv[j] = __expf(qv[j] - mx2); s2 += qv[j]; }
    s2 += __shfl_xor(s2, 16);
    s2 += __shfl_xor(s2, 32);
    const float rinv = 1.0f / s2;
    float den = 0.f;
    bf16x8 af[4];
    {
        const float* ksb = ksumf + (size_t)h * DD;
        #pragma unroll
        for (int ks = 0; ks < 4; ++ks) {
            const int dd0 = ks * 32 + g * 8;
            float4 k0 = *(const float4*)(ksb + dd0);
            float4 k1 = *(const float4*)(ksb + dd0 + 4);
            float kk[8] = {k0.x, k0.y, k0.z, k0.w, k1.x, k1.y, k1.z, k1.w};
            #pragma unroll
            for (int j = 0; j < 8; ++j) {
                const float ql = qv[ks * 8 + j] * rinv;
                af[ks][j] = (short)f2bf(ql);
                den += ql * kk[j];
            }
        }
    }
    den += __shfl_xor(den, 16);
    den += __shfl_xor(den, 32);
    const float dinv = 1.0f / (1e-5f + den);

    f32x4 acc2[8];
    #pragma unroll
    for (int nt = 0; nt < 8; ++nt) acc2[nt] = (f32x4){0.f, 0.f, 0.f, 0.f};
    {
        const unsigned short* mrow = Mt + (size_t)h * DD * DD;
        #pragma unroll
        for (int ks = 0; ks < 4; ++ks) {
            #pragma unroll
            for (int nt = 0; nt < 8; ++nt) {
                bf16x8 bf = *(const bf16x8*)&mrow[(size_t)(nt * 16 + l15) * DD + (ks * 4 + g) * 8];
                acc2[nt] = __builtin_amdgcn_mfma_f32_16x16x32_bf16(af[ks], bf, acc2[nt], 0, 0, 0);
            }
        }
    }

    // ---- combine + bias, single store ----
    float bias[8];
    #pragma unroll
    for (int nt = 0; nt < 8; ++nt) bias[nt] = pb[nt * 16 + l15];
    #pragma unroll
    for (int r = 0; r < 4; ++r) {
        const float linv = 1.0f / __shfl(l_run, g * 4 + r);
        const float di = __shfl(dinv, g * 4 + r);
        const int grow = nq * BLK + q0 + g * 4 + r;
        float* dst = out + ((size_t)grow * HH + h) * DD + l15;
        #pragma unroll
        for (int nt = 0; nt < 8; ++nt)
            dst[nt * 16] = Oacc[nt][r] * linv + acc2[nt][r] * di + bias[nt];
    }
}

extern "C" void kernel_launch(void* const* d_in, const int* in_sizes, int n_in,
                              void* d_out, int out_size, void* d_ws, size_t ws_size,
                              hipStream_t stream)
{
    (void)in_sizes; (void)n_in; (void)out_size; (void)ws_size;
    const float* q  = (const float*)d_in[0];
    const float* k  = (const float*)d_in[1];
    const float* v  = (const float*)d_in[2];
    const float* pw = (const float*)d_in[3];
    const float* pb = (const float*)d_in[4];
    float* out = (float*)d_out;
    char* ws = (char*)d_ws;
    size_t off = 0;
    int*   lut   = (int*)(ws + off);   off += (size_t)HH * NBLK * TOPK * 4;
    float* qb    = (float*)(ws + off); off += (size_t)HH * NBLK * DD * 4;
    float* kb    = (float*)(ws + off); off += (size_t)HH * NBLK * DD * 4;
    unsigned short* kvp = (unsigned short*)(ws + off); off += (size_t)HH * NCHUNK * DD * DD * 2;
    float* ksp   = (float*)(ws + off); off += (size_t)HH * NCHUNK * 4 * DD * 4;
    unsigned short* Mt = (unsigned short*)(ws + off); off += (size_t)HH * DD * DD * 2;
    float* ksumf = (float*)(ws + off); off += (size_t)HH * DD * 4;
    unsigned short* kb16 = (unsigned short*)(ws + off); off += (size_t)HH * LLEN * DD * 2;
    unsigned short* vt16 = (unsigned short*)(ws + off); off += (size_t)HH * LLEN * DD * 2;

    convert_pool<<<dim3(NBLK, HH), 256, 0, stream>>>(q, k, v, kb16, vt16, qb, kb);
    kv_topk<<<HH * NCHUNK + HH, 256, 0, stream>>>(kb16, vt16, kvp, ksp, qb, kb, lut);
    reduce_M<<<dim3(HH, 4), 256, 0, stream>>>(kvp, ksp, pw, Mt, ksumf);
    sla_attn<<<NBLK * HH, 256, 0, stream>>>(q, kb16, vt16, lut, Mt, ksumf, pb, out);
}

// Round 18
// 123.921 us; speedup vs baseline: 1.1024x; 1.0580x over previous
//
#include <hip/hip_runtime.h>
#include <math.h>

#define HH 24
#define LLEN 2048
#define DD 128
#define BLK 64
#define NBLK 32
#define TOPK 16
#define NCHUNK 16

typedef __attribute__((ext_vector_type(8))) short bf16x8;
typedef __attribute__((ext_vector_type(4))) float f32x4;

typedef unsigned int u32_g __attribute__((address_space(1)));
typedef unsigned int u32_l __attribute__((address_space(3)));

__device__ __forceinline__ unsigned short f2bf(float f) {
    unsigned u = __builtin_bit_cast(unsigned, f);
    unsigned r = (u + 0x7FFFu + ((u >> 16) & 1u)) >> 16;
    return (unsigned short)r;
}
__device__ __forceinline__ float bf2f(unsigned short b) {
    unsigned u = ((unsigned)b) << 16;
    return __builtin_bit_cast(float, u);
}
// async 16B/lane global->LDS: lds base is WAVE-UNIFORM (lane0); HW adds lane*16.
__device__ __forceinline__ void gload16(unsigned short* lds, const unsigned short* g) {
    __builtin_amdgcn_global_load_lds((const u32_g*)g, (u32_l*)lds, 16, 0, 0);
}

// ---------------- 1: convert K/V to bf16 (pre-swizzled) + block pooling (r11) ----------------
// kb16[h][l][chunk^(l&7)] row-major bf16; vt16[h][ktile][d][keychunk^(d&7)] transposed bf16.
__global__ __launch_bounds__(256) void convert_pool(
    const float* __restrict__ q, const float* __restrict__ k, const float* __restrict__ v,
    unsigned short* __restrict__ kb16, unsigned short* __restrict__ vt16,
    float* __restrict__ qb, float* __restrict__ kb)
{
    const int nb = blockIdx.x, h = blockIdx.y;
    const int l0 = nb * BLK;
    const int tid = threadIdx.x;
    __shared__ unsigned short vt_s[DD * BLK];  // 16 KB

    // ---- K convert: swizzled row writes ----
    {
        const int r = tid >> 2, c0 = (tid & 3) * 4;
        const float* kp = k + ((size_t)(l0 + r) * HH + h) * DD + c0 * 8;
        unsigned short* krow = kb16 + ((size_t)h * LLEN + l0 + r) * DD;
        #pragma unroll
        for (int j = 0; j < 4; ++j) {
            float4 a = *(const float4*)(kp + j * 8);
            float4 c = *(const float4*)(kp + j * 8 + 4);
            unsigned short tmp[8] = {f2bf(a.x), f2bf(a.y), f2bf(a.z), f2bf(a.w),
                                     f2bf(c.x), f2bf(c.y), f2bf(c.z), f2bf(c.w)};
            const int chunk = (c0 + j) ^ (r & 7);
            *(bf16x8*)&krow[chunk * 8] = *(bf16x8*)tmp;
        }
    }
    // ---- V transpose via LDS bounce (packed key-pair u32 writes, swizzled) ----
    {
        const int kp2 = tid >> 3, dgb = tid & 7;
        const float* v0p = v + ((size_t)(l0 + kp2 * 2) * HH + h) * DD;
        const float* v1p = v0p + (size_t)HH * DD;
        #pragma unroll
        for (int j2 = 0; j2 < 4; ++j2) {
            const int d0 = dgb * 4 + j2 * 32;
            float4 a = *(const float4*)(v0p + d0);
            float4 c = *(const float4*)(v1p + d0);
            float a4[4] = {a.x, a.y, a.z, a.w}, c4[4] = {c.x, c.y, c.z, c.w};
            #pragma unroll
            for (int i = 0; i < 4; ++i) {
                unsigned pak = (unsigned)f2bf(a4[i]) | ((unsigned)f2bf(c4[i]) << 16);
                const int d = d0 + i;
                const int chunk = (kp2 >> 2) ^ (d & 7);
                *(unsigned*)&vt_s[d * BLK + chunk * 8 + (kp2 & 3) * 2] = pak;
            }
        }
    }
    __syncthreads();
    // copy-out keeps the swizzle: LDS stage in sla_attn is a linear copy (rule #21)
    {
        bf16x8* dstv = (bf16x8*)(vt16 + (size_t)(h * NBLK + nb) * DD * BLK);
        const bf16x8* srcv = (const bf16x8*)vt_s;
        #pragma unroll
        for (int j = 0; j < 4; ++j) dstv[tid * 4 + j] = srcv[tid * 4 + j];
    }
    __syncthreads();
    // ---- block-sum pooling (L1-hot re-read) ----
    {
        float* ps = (float*)vt_s;
        const int d = tid & 127, half = tid >> 7;
        const size_t rs = (size_t)HH * DD;
        const float* qp = q + ((size_t)(l0 + half * 32) * HH + h) * DD + d;
        const float* kp = k + ((size_t)(l0 + half * 32) * HH + h) * DD + d;
        float sq = 0.f, sk = 0.f;
        #pragma unroll 8
        for (int i = 0; i < 32; ++i) { sq += qp[i * rs]; sk += kp[i * rs]; }
        ps[half * 128 + d] = sq;
        ps[256 + half * 128 + d] = sk;
        __syncthreads();
        if (half == 0) {
            qb[((size_t)h * NBLK + nb) * DD + d] = ps[d] + ps[128 + d];
            kb[((size_t)h * NBLK + nb) * DD + d] = ps[256 + d] + ps[384 + d];
        }
    }
}

// ---------------- 2: FUSED kvsum-partials GEMM + topk (r17, kept) ----------------
__global__ __launch_bounds__(256, 2) void kv_topk(
    const unsigned short* __restrict__ kb16, const unsigned short* __restrict__ vt16,
    unsigned short* __restrict__ kvp, float* __restrict__ ksp,
    const float* __restrict__ qb, const float* __restrict__ kb, int* __restrict__ lut)
{
    __shared__ unsigned short smem[DD * DD];  // 32 KB, aliased by both paths
    const int bid = blockIdx.x;
    const int tid = threadIdx.x;

    if (bid < HH * NCHUNK) {
        // ================= kv partial: klT . V over 128 rows =================
        const int h = bid >> 4, c = bid & 15;
        unsigned short* klT = smem;
        const int quad = tid >> 3, dpart = tid & 7;
        const int d0 = dpart * 16;
        const int wid = tid >> 6, lane = tid & 63;
        const int l15 = lane & 15, g = lane >> 4;

        f32x4 acc[2][8];
        #pragma unroll
        for (int mi = 0; mi < 2; ++mi)
            #pragma unroll
            for (int nt = 0; nt < 8; ++nt) acc[mi][nt] = (f32x4){0.f, 0.f, 0.f, 0.f};
        float ksa[16];
        #pragma unroll
        for (int j = 0; j < 16; ++j) ksa[j] = 0.f;

        const int l0 = c * DD;
        {
            const int lr = quad * 4;
            float rows[4][16];
            #pragma unroll
            for (int i = 0; i < 4; ++i) {
                const unsigned short* krow = kb16 + ((size_t)h * LLEN + l0 + lr + i) * DD;
                const int rb = (lr + i) & 7;
                bf16x8 c0v = *(const bf16x8*)&krow[(((d0 >> 3)) ^ rb) * 8];
                bf16x8 c1v = *(const bf16x8*)&krow[(((d0 >> 3) + 1) ^ rb) * 8];
                #pragma unroll
                for (int j = 0; j < 8; ++j) {
                    rows[i][j]     = bf2f((unsigned short)c0v[j]);
                    rows[i][8 + j] = bf2f((unsigned short)c1v[j]);
                }
            }
            #pragma unroll
            for (int i = 0; i < 4; ++i) {
                float mx = -1e30f;
                #pragma unroll
                for (int j = 0; j < 16; ++j) mx = fmaxf(mx, rows[i][j]);
                mx = fmaxf(mx, __shfl_xor(mx, 1));
                mx = fmaxf(mx, __shfl_xor(mx, 2));
                mx = fmaxf(mx, __shfl_xor(mx, 4));
                float s = 0.f;
                #pragma unroll
                for (int j = 0; j < 16; ++j) { rows[i][j] = __expf(rows[i][j] - mx); s += rows[i][j]; }
                s += __shfl_xor(s, 1);
                s += __shfl_xor(s, 2);
                s += __shfl_xor(s, 4);
                const float rinv = 1.0f / s;
                #pragma unroll
                for (int j = 0; j < 16; ++j) { rows[i][j] *= rinv; ksa[j] += rows[i][j]; }
            }
            #pragma unroll
            for (int j = 0; j < 16; ++j) {
                const int d = d0 + j;
                unsigned long long pk =
                    (unsigned long long)f2bf(rows[0][j]) |
                    ((unsigned long long)f2bf(rows[1][j]) << 16) |
                    ((unsigned long long)f2bf(rows[2][j]) << 32) |
                    ((unsigned long long)f2bf(rows[3][j]) << 48);
                const int chunk = (quad >> 1) ^ (d & 7);
                *(unsigned long long*)&klT[d * DD + chunk * 8 + (quad & 1) * 4] = pk;
            }
        }
        __syncthreads();
        const int bkt = c * 2;
        #pragma unroll
        for (int ks = 0; ks < 4; ++ks) {
            bf16x8 af[2];
            #pragma unroll
            for (int mi = 0; mi < 2; ++mi) {
                const int d = (wid * 2 + mi) * 16 + l15;
                const int chunk = (ks * 4 + g) ^ (d & 7);
                af[mi] = *(const bf16x8*)&klT[d * DD + chunk * 8];
            }
            const int s = ks * 4 + g;
            const int kt = bkt + (s >> 3);
            #pragma unroll
            for (int nt = 0; nt < 8; ++nt) {
                const int e = nt * 16 + l15;
                const int cc = (s & 7) ^ (e & 7);
                bf16x8 bf = *(const bf16x8*)&vt16[((size_t)(h * NBLK + kt) * DD + e) * BLK + cc * 8];
                acc[0][nt] = __builtin_amdgcn_mfma_f32_16x16x32_bf16(af[0], bf, acc[0][nt], 0, 0, 0);
                acc[1][nt] = __builtin_amdgcn_mfma_f32_16x16x32_bf16(af[1], bf, acc[1][nt], 0, 0, 0);
            }
        }
        unsigned short* op = kvp + (size_t)(h * NCHUNK + c) * DD * DD;
        #pragma unroll
        for (int mi = 0; mi < 2; ++mi)
            #pragma unroll
            for (int nt = 0; nt < 8; ++nt)
                #pragma unroll
                for (int r = 0; r < 4; ++r)
                    op[(size_t)((wid * 2 + mi) * 16 + g * 4 + r) * DD + nt * 16 + l15] =
                        f2bf(acc[mi][nt][r]);
        #pragma unroll
        for (int j = 0; j < 16; ++j) {
            ksa[j] += __shfl_xor(ksa[j], 8);
            ksa[j] += __shfl_xor(ksa[j], 16);
            ksa[j] += __shfl_xor(ksa[j], 32);
        }
        if ((lane >> 3) == 0) {
            float* kp2 = ksp + (((size_t)h * NCHUNK + c) * 4 + wid) * DD + d0;
            #pragma unroll
            for (int j = 0; j < 16; ++j) kp2[j] = ksa[j];
        }
    } else {
        // ================= topk: block scores + top-16 LUT =================
        const int h = bid - HH * NCHUNK;
        float* kb_s = (float*)smem;
        float* sc = (float*)(smem + NBLK * DD * 2);
        for (int f = tid; f < NBLK * DD / 4; f += 256)
            ((float4*)kb_s)[f] = ((const float4*)(kb + (size_t)h * NBLK * DD))[f];
        __syncthreads();
        for (int p = tid; p < NBLK * NBLK; p += 256) {
            const int iq = p >> 5, ik = p & 31;
            const float4* qr4 = (const float4*)(qb + ((size_t)h * NBLK + iq) * DD);
            const float4* kr4 = (const float4*)&kb_s[ik * DD];
            float s = 0.f;
            for (int dq = 0; dq < DD / 4; ++dq) {
                float4 a = qr4[dq], b = kr4[dq];
                s += a.x * b.x + a.y * b.y + a.z * b.z + a.w * b.w;
            }
            sc[iq * NBLK + ik] = s;
        }
        __syncthreads();
        if (tid < NBLK) {
            const int iq = tid;
            for (int t = 0; t < TOPK; ++t) {
                float bv = -1e30f; int bi = 0;
                for (int j = 0; j < NBLK; ++j) {
                    float s = sc[iq * NBLK + j];
                    if (s > bv) { bv = s; bi = j; }
                }
                lut[((size_t)h * NBLK + iq) * TOPK + t] = bi;
                sc[iq * NBLK + bi] = -1e30f;
            }
        }
    }
}

// ---------------- 3: reduce bf16 partials; Mt = (kvsum @ W^T)^T bf16; final ksum ----------------
// Widened grid (HH, 16): 8-row strips, 384 blocks (was 96 -> only 37% of CUs busy).
__global__ __launch_bounds__(256) void reduce_M(
    const unsigned short* __restrict__ kvp, const float* __restrict__ ksp,
    const float* __restrict__ W, unsigned short* __restrict__ Mt,
    float* __restrict__ ksumf)
{
    const int h = blockIdx.x, rb = blockIdx.y;  // d-rows [rb*8, rb*8+8)
    __shared__ float kv_s[8][DD];               // 4 KB
    const int tid = threadIdx.x;
    for (int f8 = tid; f8 < 8 * DD / 8; f8 += 256) {
        float s[8];
        #pragma unroll
        for (int j = 0; j < 8; ++j) s[j] = 0.f;
        #pragma unroll
        for (int cc = 0; cc < NCHUNK; ++cc) {
            bf16x8 x = ((const bf16x8*)(kvp + (size_t)(h * NCHUNK + cc) * DD * DD
                                        + (size_t)rb * 8 * DD))[f8];
            #pragma unroll
            for (int j = 0; j < 8; ++j) s[j] += bf2f((unsigned short)x[j]);
        }
        #pragma unroll
        for (int j = 0; j < 8; ++j) ((float*)kv_s)[f8 * 8 + j] = s[j];
    }
    if (rb == 0 && tid < DD) {
        float s = 0.f;
        #pragma unroll
        for (int p = 0; p < NCHUNK * 4; ++p)
            s += ksp[((size_t)h * NCHUNK * 4 + p) * DD + tid];
        ksumf[(size_t)h * DD + tid] = s;
    }
    __syncthreads();
    const int e = tid & 127, dh = tid >> 7;   // dh in {0,1}: rows dh*4..dh*4+3
    float accm[4];
    #pragma unroll
    for (int i = 0; i < 4; ++i) accm[i] = 0.f;
    const float4* wr4 = (const float4*)(W + (size_t)e * DD);
    for (int c4 = 0; c4 < DD / 4; ++c4) {
        const float4 wv = wr4[c4];
        #pragma unroll
        for (int i = 0; i < 4; ++i) {
            const float4 kv4 = ((const float4*)&kv_s[dh * 4 + i][0])[c4];
            accm[i] += kv4.x * wv.x + kv4.y * wv.y + kv4.z * wv.z + kv4.w * wv.w;
        }
    }
    unsigned short* mp = Mt + (size_t)h * DD * DD + (size_t)e * DD + rb * 8 + dh * 4;
    #pragma unroll
    for (int ii = 0; ii < 4; ii += 2) {
        unsigned pk = (unsigned)f2bf(accm[ii]) | ((unsigned)f2bf(accm[ii + 1]) << 16);
        *(unsigned*)&mp[ii] = pk;
    }
}

// ---------------- 4: fused sparse attention + linear epilogue (r11 exact, known-best) ----------------
// 4 waves x 16 queries, 40 KB LDS, counted-vmcnt 2-phase, (256,3). Defer-max REVERTED
// (r17: 0 time delta, +12 VGPR, +5MB scratch). Sentinels: VGPR 72, WRITE 24.58 MB.
__global__ __launch_bounds__(256, 3) void sla_attn(
    const float* __restrict__ q, const unsigned short* __restrict__ kb16,
    const unsigned short* __restrict__ vt16, const int* __restrict__ lut,
    const unsigned short* __restrict__ Mt, const float* __restrict__ ksumf,
    const float* __restrict__ pb, float* __restrict__ out)
{
    const int b = blockIdx.x;
    const int slot = b >> 3;
    const int h = (b & 7) + 8 * (slot >> 5);
    const int nq = slot & 31;

    __shared__ unsigned short Ks[BLK * DD];      // 16 KB, K[it]
    __shared__ unsigned short Vt[DD * BLK];      // 16 KB, V[it]
    __shared__ unsigned short Ps[4 * 16 * BLK];  // 8 KB  -> 40 KB total

    const int tid = threadIdx.x;
    const int wid = tid >> 6, lane = tid & 63;
    const int l15 = lane & 15, g = lane >> 4;
    const int q0 = wid * 16;

    // ---- Q fragments: scale folded, single bf16, stationary ----
    bf16x8 qf[4];
    {
        const float scale = 0.08838834764831845f;
        const int qrow = nq * BLK + q0 + l15;
        const float* qp = q + ((size_t)qrow * HH + h) * DD;
        #pragma unroll
        for (int ks = 0; ks < 4; ++ks) {
            const int d0 = ks * 32 + g * 8;
            float4 a = *(const float4*)(qp + d0);
            float4 c = *(const float4*)(qp + d0 + 4);
            float vv[8] = {a.x, a.y, a.z, a.w, c.x, c.y, c.z, c.w};
            #pragma unroll
            for (int j = 0; j < 8; ++j)
                qf[ks][j] = (short)f2bf(vv[j] * scale);
        }
    }

    f32x4 Oacc[8];
    #pragma unroll
    for (int nt = 0; nt < 8; ++nt) Oacc[nt] = (f32x4){0.f, 0.f, 0.f, 0.f};
    float m_run = -1e30f, l_run = 0.f;

    const int* lrow = lut + ((size_t)h * NBLK + nq) * TOPK;

    // prologue: issue K[0] (wave w stages slices 4w..4w+3, 1 KB each)
    {
        const int kb0 = lrow[0];
        const unsigned short* kg = kb16 + ((size_t)h * LLEN + (size_t)kb0 * BLK) * DD;
        #pragma unroll
        for (int i = 0; i < 4; ++i) {
            const int is = wid * 4 + i;
            gload16(&Ks[is * 512], kg + is * 512 + lane * 8);
        }
    }

    for (int it = 0; it < TOPK; ++it) {
        const int kbI = lrow[it];
        __builtin_amdgcn_s_barrier();   // prev iter's V/Ps readers done
        // ---- stage V[it]; outstanding: K[it](4) + V[it](4) ----
        {
            const unsigned short* vg = vt16 + (size_t)(h * NBLK + kbI) * DD * BLK;
            #pragma unroll
            for (int i = 0; i < 4; ++i) {
                const int is = wid * 4 + i;
                gload16(&Vt[is * 512], vg + is * 512 + lane * 8);
            }
        }
        asm volatile("s_waitcnt vmcnt(4)" ::: "memory");  // K[it] landed; V still in flight
        __builtin_amdgcn_sched_barrier(0);

        // ---- S^T = K . Q^T (16 MFMA) ----
        f32x4 sacc[4];
        #pragma unroll
        for (int mt = 0; mt < 4; ++mt) sacc[mt] = (f32x4){0.f, 0.f, 0.f, 0.f};
        __builtin_amdgcn_s_setprio(1);
        #pragma unroll
        for (int ks = 0; ks < 4; ++ks) {
            #pragma unroll
            for (int mt = 0; mt < 4; ++mt) {
                const int row = mt * 16 + l15;
                const int chunk = (ks * 4 + g) ^ (row & 7);
                bf16x8 kf = *(const bf16x8*)&Ks[row * DD + chunk * 8];
                sacc[mt] = __builtin_amdgcn_mfma_f32_16x16x32_bf16(kf, qf[ks], sacc[mt], 0, 0, 0);
            }
        }
        __builtin_amdgcn_s_setprio(0);

        __builtin_amdgcn_s_barrier();   // all waves consumed K[it]
        // ---- prefetch K[it+1]; spans softmax + PV + next top barrier ----
        if (it + 1 < TOPK) {
            const int kbN = lrow[it + 1];
            const unsigned short* kg = kb16 + ((size_t)h * LLEN + (size_t)kbN * BLK) * DD;
            #pragma unroll
            for (int i = 0; i < 4; ++i) {
                const int is = wid * 4 + i;
                gload16(&Ks[is * 512], kg + is * 512 + lane * 8);
            }
        }

        // ---- online softmax ----
        float sv[16];
        #pragma unroll
        for (int mt = 0; mt < 4; ++mt)
            #pragma unroll
            for (int r = 0; r < 4; ++r) sv[mt * 4 + r] = sacc[mt][r];
        float mx = -1e30f;
        #pragma unroll
        for (int i = 0; i < 16; ++i) mx = fmaxf(mx, sv[i]);
        mx = fmaxf(mx, __shfl_xor(mx, 16));
        mx = fmaxf(mx, __shfl_xor(mx, 32));
        const float mnew = fmaxf(m_run, mx);
        const float alpha = __expf(m_run - mnew);
        float ssum = 0.f;
        #pragma unroll
        for (int i = 0; i < 16; ++i) { sv[i] = __expf(sv[i] - mnew); ssum += sv[i]; }
        ssum += __shfl_xor(ssum, 16);
        ssum += __shfl_xor(ssum, 32);
        l_run = l_run * alpha + ssum;
        m_run = mnew;

        // ---- P to LDS (own-wave region; in-wave ordering) ----
        {
            unsigned short* pw = Ps + wid * (16 * BLK) + l15 * BLK;
            #pragma unroll
            for (int mt = 0; mt < 4; ++mt) {
                #pragma unroll
                for (int pr = 0; pr < 2; ++pr) {
                    const int key = mt * 16 + g * 4 + pr * 2;
                    unsigned pak = (unsigned)f2bf(sv[mt * 4 + pr * 2])
                                 | ((unsigned)f2bf(sv[mt * 4 + pr * 2 + 1]) << 16);
                    const int chunk = (key >> 3) ^ (l15 & 7);
                    *(unsigned*)&pw[chunk * 8 + (key & 7)] = pak;
                }
            }
        }

        // ---- V[it] landed? (oldest 4 = V; K[it+1] stays in flight) ----
        if (it + 1 < TOPK) {
            asm volatile("s_waitcnt vmcnt(4)" ::: "memory");
        } else {
            asm volatile("s_waitcnt vmcnt(0)" ::: "memory");
        }
        __builtin_amdgcn_sched_barrier(0);

        // ---- O rescale + PV ----
        {
            float ar[4];
            #pragma unroll
            for (int r = 0; r < 4; ++r) ar[r] = __shfl(alpha, g * 4 + r);
            #pragma unroll
            for (int nt = 0; nt < 8; ++nt) {
                Oacc[nt][0] *= ar[0]; Oacc[nt][1] *= ar[1];
                Oacc[nt][2] *= ar[2]; Oacc[nt][3] *= ar[3];
            }
            const unsigned short* prd = Ps + wid * (16 * BLK) + l15 * BLK;
            #pragma unroll
            for (int ks2 = 0; ks2 < 2; ++ks2) {
                const int pch = (g + 4 * ks2) ^ (l15 & 7);
                bf16x8 pa = *(const bf16x8*)&prd[pch * 8];
                __builtin_amdgcn_s_setprio(1);
                #pragma unroll
                for (int nt = 0; nt < 8; ++nt) {
                    const int drow = nt * 16 + l15;
                    const int vch = (g + 4 * ks2) ^ (drow & 7);
                    bf16x8 vf = *(const bf16x8*)&Vt[drow * BLK + vch * 8];
                    Oacc[nt] = __builtin_amdgcn_mfma_f32_16x16x32_bf16(pa, vf, Oacc[nt], 0, 0, 0);
                }
                __builtin_amdgcn_s_setprio(0);
            }
        }
    }

    // ---- fused linear-attn epilogue: ql softmax + 32 MFMAs vs Mt (L2-hot global) ----
    float qv[32];
    {
        const float iscale = 11.313708498984761f;  // sqrt(D): undo folded scale
        #pragma unroll
        for (int ks = 0; ks < 4; ++ks)
            #pragma unroll
            for (int j = 0; j < 8; ++j)
                qv[ks * 8 + j] = bf2f((unsigned short)qf[ks][j]) * iscale;
    }
    float mx2 = -1e30f;
    #pragma unroll
    for (int j = 0; j < 32; ++j) mx2 = fmaxf(mx2, qv[j]);
    mx2 = fmaxf(mx2, __shfl_xor(mx2, 16));
    mx2 = fmaxf(mx2, __shfl_xor(mx2, 32));
    float s2 = 0.f;
    #pragma unroll
    for (int j = 0; j < 32; ++j) { qv[j] = __expf(qv[j] - mx2); s2 += qv[j]; }
    s2 += __shfl_xor(s2, 16);
    s2 += __shfl_xor(s2, 32);
    const float rinv = 1.0f / s2;
    float den = 0.f;
    bf16x8 af[4];
    {
        const float* ksb = ksumf + (size_t)h * DD;
        #pragma unroll
        for (int ks = 0; ks < 4; ++ks) {
            const int dd0 = ks * 32 + g * 8;
            float4 k0 = *(const float4*)(ksb + dd0);
            float4 k1 = *(const float4*)(ksb + dd0 + 4);
            float kk[8] = {k0.x, k0.y, k0.z, k0.w, k1.x, k1.y, k1.z, k1.w};
            #pragma unroll
            for (int j = 0; j < 8; ++j) {
                const float ql = qv[ks * 8 + j] * rinv;
                af[ks][j] = (short)f2bf(ql);
                den += ql * kk[j];
            }
        }
    }
    den += __shfl_xor(den, 16);
    den += __shfl_xor(den, 32);
    const float dinv = 1.0f / (1e-5f + den);

    f32x4 acc2[8];
    #pragma unroll
    for (int nt = 0; nt < 8; ++nt) acc2[nt] = (f32x4){0.f, 0.f, 0.f, 0.f};
    {
        const unsigned short* mrow = Mt + (size_t)h * DD * DD;
        #pragma unroll
        for (int ks = 0; ks < 4; ++ks) {
            #pragma unroll
            for (int nt = 0; nt < 8; ++nt) {
                bf16x8 bf = *(const bf16x8*)&mrow[(size_t)(nt * 16 + l15) * DD + (ks * 4 + g) * 8];
                acc2[nt] = __builtin_amdgcn_mfma_f32_16x16x32_bf16(af[ks], bf, acc2[nt], 0, 0, 0);
            }
        }
    }

    // ---- combine + bias, single store ----
    float bias[8];
    #pragma unroll
    for (int nt = 0; nt < 8; ++nt) bias[nt] = pb[nt * 16 + l15];
    #pragma unroll
    for (int r = 0; r < 4; ++r) {
        const float linv = 1.0f / __shfl(l_run, g * 4 + r);
        const float di = __shfl(dinv, g * 4 + r);
        const int grow = nq * BLK + q0 + g * 4 + r;
        float* dst = out + ((size_t)grow * HH + h) * DD + l15;
        #pragma unroll
        for (int nt = 0; nt < 8; ++nt)
            dst[nt * 16] = Oacc[nt][r] * linv + acc2[nt][r] * di + bias[nt];
    }
}

extern "C" void kernel_launch(void* const* d_in, const int* in_sizes, int n_in,
                              void* d_out, int out_size, void* d_ws, size_t ws_size,
                              hipStream_t stream)
{
    (void)in_sizes; (void)n_in; (void)out_size; (void)ws_size;
    const float* q  = (const float*)d_in[0];
    const float* k  = (const float*)d_in[1];
    const float* v  = (const float*)d_in[2];
    const float* pw = (const float*)d_in[3];
    const float* pb = (const float*)d_in[4];
    float* out = (float*)d_out;
    char* ws = (char*)d_ws;
    size_t off = 0;
    int*   lut   = (int*)(ws + off);   off += (size_t)HH * NBLK * TOPK * 4;
    float* qb    = (float*)(ws + off); off += (size_t)HH * NBLK * DD * 4;
    float* kb    = (float*)(ws + off); off += (size_t)HH * NBLK * DD * 4;
    unsigned short* kvp = (unsigned short*)(ws + off); off += (size_t)HH * NCHUNK * DD * DD * 2;
    float* ksp   = (float*)(ws + off); off += (size_t)HH * NCHUNK * 4 * DD * 4;
    unsigned short* Mt = (unsigned short*)(ws + off); off += (size_t)HH * DD * DD * 2;
    float* ksumf = (float*)(ws + off); off += (size_t)HH * DD * 4;
    unsigned short* kb16 = (unsigned short*)(ws + off); off += (size_t)HH * LLEN * DD * 2;
    unsigned short* vt16 = (unsigned short*)(ws + off); off += (size_t)HH * LLEN * DD * 2;

    convert_pool<<<dim3(NBLK, HH), 256, 0, stream>>>(q, k, v, kb16, vt16, qb, kb);
    kv_topk<<<HH * NCHUNK + HH, 256, 0, stream>>>(kb16, vt16, kvp, ksp, qb, kb, lut);
    reduce_M<<<dim3(HH, 16), 256, 0, stream>>>(kvp, ksp, pw, Mt, ksumf);
    sla_attn<<<NBLK * HH, 256, 0, stream>>>(q, kb16, vt16, lut, Mt, ksumf, pb, out);
}